// Round 9
// baseline (194.958 us; speedup 1.0000x reference)
//
#include <hip/hip_runtime.h>
#include <cstdint>

// Problem constants
#define BB 4
#define TT 2048      // TQ == TK
#define DD 512
#define HH 8
#define DH 64
#define NT (TT / 64) // KV tiles of 64
#define LOG2E 1.4426950408889634f

using bf16x8 = __attribute__((ext_vector_type(8))) __bf16;
using f32x4  = __attribute__((ext_vector_type(4))) float;
using f32x16 = __attribute__((ext_vector_type(16))) float;
using us8    = __attribute__((ext_vector_type(8))) unsigned short;
using us4    = __attribute__((ext_vector_type(4))) unsigned short;
using u32x2  = __attribute__((ext_vector_type(2))) unsigned int;

typedef const __attribute__((address_space(1))) unsigned int* as1cp;
typedef __attribute__((address_space(3))) unsigned int* as3p;

__device__ __forceinline__ void gload16(const void* g, void* l) {
  __builtin_amdgcn_global_load_lds((as1cp)(uintptr_t)g,
                                   (as3p)(unsigned int)(uintptr_t)l, 16, 0, 0);
}

__device__ __forceinline__ unsigned short f2bf(float x) {
  unsigned int u = __float_as_uint(x);
  u += 0x7fffu + ((u >> 16) & 1u);
  return (unsigned short)(u >> 16);
}
__device__ __forceinline__ float bf2f(unsigned short u) {
  return __uint_as_float(((unsigned int)u) << 16);
}
__device__ __forceinline__ f32x4 MFMA(bf16x8 a, bf16x8 b, f32x4 c) {
  return __builtin_amdgcn_mfma_f32_16x16x32_bf16(a, b, c, 0, 0, 0);
}
__device__ __forceinline__ f32x16 MFMA32(bf16x8 a, bf16x8 b, f32x16 c) {
  return __builtin_amdgcn_mfma_f32_32x32x16_bf16(a, b, c, 0, 0, 0);
}

#define WAITVM(N) asm volatile("s_waitcnt vmcnt(" #N ")" ::: "memory")
#define RAWBAR() asm volatile("s_barrier" ::: "memory")

// ---------------- 1. prep: convert inputs to bf16 + weight transpose ----------------
__global__ __launch_bounds__(256) void prep_kernel(const float4* __restrict__ q,
                                                   const float4* __restrict__ k,
                                                   us4* __restrict__ qb,
                                                   us4* __restrict__ kb,
                                                   const float* __restrict__ Wq,
                                                   const float* __restrict__ Wk,
                                                   const float* __restrict__ Wv,
                                                   unsigned short* __restrict__ Wt) {
  __shared__ float tile[32][33];
  int id = blockIdx.x;
  if (id < 4096) {
    size_t i = (size_t)id * 256 + threadIdx.x;
    float4 a = q[i];
    us4 o; o[0] = f2bf(a.x); o[1] = f2bf(a.y); o[2] = f2bf(a.z); o[3] = f2bf(a.w);
    qb[i] = o;
    float4 b = k[i];
    us4 p; p[0] = f2bf(b.x); p[1] = f2bf(b.y); p[2] = f2bf(b.z); p[3] = f2bf(b.w);
    kb[i] = p;
  } else {
    int id2 = id - 4096;
    int z = id2 >> 8, rem = id2 & 255;
    const float* W = (z == 0) ? Wq : (z == 1) ? Wk : Wv;
    int k0 = (rem & 15) * 32, n0 = (rem >> 4) * 32;
    int r = threadIdx.x >> 5, c = threadIdx.x & 31;
#pragma unroll
    for (int p = 0; p < 4; ++p)
      tile[r + p * 8][c] = W[(size_t)(k0 + r + p * 8) * DD + n0 + c];
    __syncthreads();
    unsigned short* o = Wt + (size_t)z * DD * DD;
#pragma unroll
    for (int p = 0; p < 4; ++p)
      o[(size_t)(n0 + r + p * 8) * DD + k0 + c] = f2bf(tile[c][r + p * 8]);
  }
}

// ---------------- 2. projection GEMM + fused masks ----------------
// out = relu(A @ W + b) [* 0.125*log2e for Q]. Each wave covers 64 token-rows
// (one 64-tile) x 64 cols (one head) -> K-gemm waves emit kbits[bh][tile],
// Q-gemm waves emit qmask rows. V-gemm waves skip mask work.
#define GSTAGE(kt2, pbuf)                                                    \
  {                                                                          \
    int t_ = threadIdx.x;                                                    \
    _Pragma("unroll")                                                        \
    for (int it_ = 0; it_ < 2; ++it_) {                                      \
      int c_ = t_ + it_ * 256;                                               \
      gload16(A  + (size_t)(mb + (c_ >> 2)) * DD + (kt2) * 32 + (c_ & 3) * 8,\
              &As[pbuf][(size_t)c_ * 8]);                                    \
      gload16(Bt + (size_t)(nb + (c_ >> 2)) * DD + (kt2) * 32 + (c_ & 3) * 8,\
              &Bs[pbuf][(size_t)c_ * 8]);                                    \
    }                                                                        \
  }

__global__ __launch_bounds__(256) void gemm_proj(const unsigned short* __restrict__ qb,
                                                 const unsigned short* __restrict__ kb,
                                                 const unsigned short* __restrict__ Wt,
                                                 const float* __restrict__ bq,
                                                 const float* __restrict__ bk,
                                                 const float* __restrict__ bv,
                                                 unsigned short* __restrict__ Qp,
                                                 unsigned short* __restrict__ Kp,
                                                 unsigned short* __restrict__ Vp,
                                                 float* __restrict__ qmask,
                                                 uint2* __restrict__ kbits) {
  int z = blockIdx.z;
  const unsigned short* A  = (z == 0) ? qb : kb;
  const unsigned short* Bt = Wt + (size_t)z * DD * DD;
  const float* bias = (z == 0) ? bq : (z == 1) ? bk : bv;
  unsigned short* out = (z == 0) ? Qp : (z == 1) ? Kp : Vp;
  const float osc = (z == 0) ? 0.125f * LOG2E : 1.0f;  // scores in log2 domain

  __shared__ __align__(16) unsigned short As[2][128 * 32];
  __shared__ __align__(16) unsigned short Bs[2][128 * 32];

  int mb = blockIdx.x * 128, nb = blockIdx.y * 128;
  int w = threadIdx.x >> 6, lane = threadIdx.x & 63;
  int l15 = lane & 15, lg = lane >> 4;
  int wr = (w >> 1) * 64, wc = (w & 1) * 64;

  f32x4 acc[4][4] = {};

  GSTAGE(0, 0);
  for (int kt = 0; kt < DD / 32; ++kt) {
    int pb2 = kt & 1;
    if (kt + 1 < DD / 32) {
      GSTAGE(kt + 1, pb2 ^ 1);
      WAITVM(4);
    } else {
      WAITVM(0);
    }
    RAWBAR();

    bf16x8 af[4], bf[4];
#pragma unroll
    for (int m = 0; m < 4; ++m)
      af[m] = *(const bf16x8*)&As[pb2][(wr + m * 16 + l15) * 32 + lg * 8];
#pragma unroll
    for (int n = 0; n < 4; ++n)
      bf[n] = *(const bf16x8*)&Bs[pb2][(wc + n * 16 + l15) * 32 + lg * 8];
#pragma unroll
    for (int m = 0; m < 4; ++m)
#pragma unroll
      for (int n = 0; n < 4; ++n)
        acc[m][n] = MFMA(af[m], bf[n], acc[m][n]);

    if (kt + 1 < DD / 32) RAWBAR();
  }

  // epilogue + per-row head-sum (rows: wr+m*16+lg*4+i, head cols: wc..wc+63)
  float rs_[16];
#pragma unroll
  for (int j = 0; j < 16; ++j) rs_[j] = 0.f;
#pragma unroll
  for (int m = 0; m < 4; ++m)
#pragma unroll
    for (int n = 0; n < 4; ++n)
#pragma unroll
      for (int i = 0; i < 4; ++i) {
        int row = mb + wr + m * 16 + lg * 4 + i;
        int col = nb + wc + n * 16 + l15;
        float v = fmaxf(acc[m][n][i] + bias[col], 0.f);
        rs_[m * 4 + i] += v;
        out[(size_t)row * DD + col] = f2bf(v * osc);
      }

  if (z < 2) {
    // reduce each row-sum across the 16 l15 lanes
#pragma unroll
    for (int j = 0; j < 16; ++j) {
      rs_[j] += __shfl_xor(rs_[j], 1);
      rs_[j] += __shfl_xor(rs_[j], 2);
      rs_[j] += __shfl_xor(rs_[j], 4);
      rs_[j] += __shfl_xor(rs_[j], 8);
    }
    int gr0 = mb + wr;                       // first row of this wave's 64-row tile
    int b = gr0 >> 11, tpos0 = gr0 & (TT - 1);
    int h = (nb + wc) >> 6;
    int bh = b * HH + h;
    if (z == 0) {
      if (l15 == 0) {
#pragma unroll
        for (int m = 0; m < 4; ++m)
#pragma unroll
          for (int i = 0; i < 4; ++i) {
            int tpos = tpos0 + m * 16 + lg * 4 + i;
            qmask[(size_t)bh * TT + tpos] = (rs_[m * 4 + i] > 0.f) ? 1.f : 0.f;
          }
      }
    } else {
      unsigned long long wloc = 0;
#pragma unroll
      for (int m = 0; m < 4; ++m)
#pragma unroll
        for (int i = 0; i < 4; ++i)
          if (rs_[m * 4 + i] > 0.f)
            wloc |= 1ull << (m * 16 + lg * 4 + i);
      wloc |= __shfl_xor(wloc, 16);
      wloc |= __shfl_xor(wloc, 32);
      if (lane == 0)
        kbits[bh * NT + (tpos0 >> 6)] =
            make_uint2((unsigned int)wloc, (unsigned int)(wloc >> 32));
    }
  }
}

// ---------------- 3. V transpose: Vp[B*TK, D] -> Vt[B, D, TK] ----------------
__global__ __launch_bounds__(256) void post_v(const unsigned short* __restrict__ Vp,
                                              unsigned short* __restrict__ Vt) {
  __shared__ unsigned short tile[64][72];
  int id = blockIdx.x;
  int b = id >> 8, k0 = (id & 31) * 64, d0 = ((id >> 5) & 7) * 64;
  int t = threadIdx.x;
  int r = t >> 3, c8 = (t & 7) * 8;
#pragma unroll
  for (int p = 0; p < 2; ++p) {
    int row = r + p * 32;
    us8 v = *(const us8*)&Vp[(size_t)(b * TT + k0 + row) * DD + d0 + c8];
#pragma unroll
    for (int j = 0; j < 8; ++j) tile[row][c8 + j] = v[j];
  }
  __syncthreads();
#pragma unroll
  for (int p = 0; p < 2; ++p) {
    int dr = r + p * 32;
    us8 o;
#pragma unroll
    for (int j = 0; j < 8; ++j) o[j] = tile[c8 + j][dr];
    *(us8*)&Vt[((size_t)b * DD + d0 + dr) * TT + k0 + c8] = o;
  }
}

// ---------------- 4. flash attention: static-shift softmax (no max tracking) ----------------
// Q,K >= 0 (relu) -> unmasked scores in [0, ~small]; softmax shift-invariance
// lets us use p = exp2(s) directly: no max tree, no rescale, no per-tile
// cross-lane ops (l accumulates lane-locally, one permlane at the end).
// K rows staged with kpos bits 2,3 swapped -> s-reg r of sN = score for kpos
// 32N+16(r>>3)+8h2+(r&7) = the PV B-frag order -> pack = plain bf16 casts.
#define STAGE(tt, pbuf)                                                      \
  {                                                                          \
    int c0_ = threadIdx.x;                                                   \
    _Pragma("unroll")                                                        \
    for (int it_ = 0; it_ < 2; ++it_) {                                      \
      int c_ = c0_ + it_ * 256;                                              \
      int r_ = c_ >> 3, j_ = c_ & 7;                                         \
      int js_ = j_ ^ (r_ & 7);                                               \
      int kr_ = (r_ & ~12) | ((r_ & 4) << 1) | ((r_ & 8) >> 1);              \
      gload16(kg + (size_t)((tt) * 64 + kr_) * DD + js_ * 8,                 \
              &KsBuf[pbuf][(size_t)c_ * 8]);                                 \
      gload16(vg + (size_t)r_ * TT + (tt) * 64 + js_ * 8,                    \
              &VsBuf[pbuf][(size_t)c_ * 8]);                                 \
    }                                                                        \
  }

__global__ __launch_bounds__(256) void attn_kernel(
    const unsigned short* __restrict__ Qp,
    const unsigned short* __restrict__ Kp,
    const unsigned short* __restrict__ Vt,
    const uint2* __restrict__ kbits,
    const float* __restrict__ qmask,
    unsigned short* __restrict__ O) {          // bf16 output
  __shared__ __align__(16) unsigned short KsBuf[2][64 * 64];
  __shared__ __align__(16) unsigned short VsBuf[2][64 * 64];

  const int w = threadIdx.x >> 6;
  const int lane = threadIdx.x & 63;
  const int l31 = lane & 31, h2 = lane >> 5;

  // XCD-bijective swizzle: 512 blocks -> each (b,h)'s 16 q-tiles on one XCD
  int flat = blockIdx.x;
  int wg = (flat & 7) * 64 + (flat >> 3);
  int qt = wg & 15, bh = wg >> 4;
  int h = bh & 7, b = bh >> 3;
  int q0 = qt * 128 + w * 32;

  const unsigned short* qbase =
      Qp + ((size_t)(b * TT + q0 + l31)) * DD + h * DH + h2 * 8;
  bf16x8 qf[4];
#pragma unroll
  for (int kd = 0; kd < 4; ++kd) qf[kd] = *(const bf16x8*)(qbase + kd * 16);

  const unsigned short* kg = Kp + ((size_t)b * TT) * DD + h * DH;
  const unsigned short* vg = Vt + ((size_t)(b * DD + h * DH)) * TT;
  const uint2* kb_ptr = kbits + (size_t)bh * NT;

  f32x16 oat0 = {}, oat1 = {};
  float l_i = 0.f;

  STAGE(0, 0);

  for (int t = 0; t < NT; ++t) {
    int pb = t & 1;
    if (t + 1 < NT) {
      STAGE(t + 1, pb ^ 1);
      WAITVM(4);          // tile t's 4 loads done; t+1's stay in flight
    } else {
      WAITVM(0);
    }
    RAWBAR();

    const unsigned short* ksb = &KsBuf[pb][0];
    const unsigned short* vsb = &VsBuf[pb][0];

    // K A-frags + QK^T
    bf16x8 kf0[4], kf1[4];
#pragma unroll
    for (int kd = 0; kd < 4; ++kd) {
      int x = ((kd * 2 + h2) ^ (l31 & 7)) << 3;
      kf0[kd] = *(const bf16x8*)&ksb[l31 * 64 + x];
      kf1[kd] = *(const bf16x8*)&ksb[(32 + l31) * 64 + x];
    }
    f32x16 s0 = {}, s1 = {};
    __builtin_amdgcn_s_setprio(1);
#pragma unroll
    for (int kd = 0; kd < 4; ++kd) s0 = MFMA32(kf0[kd], qf[kd], s0);
#pragma unroll
    for (int kd = 0; kd < 4; ++kd) s1 = MFMA32(kf1[kd], qf[kd], s1);
    __builtin_amdgcn_s_setprio(0);

    // V A-frags (issued here; consumed after softmax)
    bf16x8 vf0[4], vf1[4];
#pragma unroll
    for (int ks = 0; ks < 4; ++ks) {
      int x = ((ks * 2 + h2) ^ (l31 & 7)) << 3;
      vf0[ks] = *(const bf16x8*)&vsb[l31 * 64 + x];
      vf1[ks] = *(const bf16x8*)&vsb[(32 + l31) * 64 + x];
    }

    // key mask (fast path: all ones). kpos(reg r, sN) = 32N+16(r>>3)+8h2+(r&7)
    uint2 kw = kb_ptr[t];
    if ((kw.x & kw.y) != 0xffffffffu) {
#pragma unroll
      for (int r = 0; r < 16; ++r) {
        int sh = ((r >> 3) << 4) + (h2 << 3) + (r & 7);
        if (!((kw.x >> sh) & 1)) s0[r] = -1e30f;
        if (!((kw.y >> sh) & 1)) s1[r] = -1e30f;
      }
    }

    // p = exp2(s) (static shift: Q,K>=0 so s>=0, no overflow possible),
    // lane-local l accumulation (no cross-lane ops in the loop)
    float a0 = 0.f, a1 = 0.f, a2 = 0.f, a3 = 0.f;
#pragma unroll
    for (int r = 0; r < 8; ++r)  { float p = exp2f(s0[r]); s0[r] = p; a0 += p; }
#pragma unroll
    for (int r = 8; r < 16; ++r) { float p = exp2f(s0[r]); s0[r] = p; a1 += p; }
#pragma unroll
    for (int r = 0; r < 8; ++r)  { float p = exp2f(s1[r]); s1[r] = p; a2 += p; }
#pragma unroll
    for (int r = 8; r < 16; ++r) { float p = exp2f(s1[r]); s1[r] = p; a3 += p; }
    l_i += (a0 + a1) + (a2 + a3);

    // P -> bf16 B-frags: direct per-lane concatenation (bit-swap staging)
    bf16x8 pbf[4];
#pragma unroll
    for (int j = 0; j < 8; ++j) {
      pbf[0][j] = (__bf16)s0[j];
      pbf[1][j] = (__bf16)s0[8 + j];
      pbf[2][j] = (__bf16)s1[j];
      pbf[3][j] = (__bf16)s1[8 + j];
    }

    // O^T += Vt . P
    __builtin_amdgcn_s_setprio(1);
#pragma unroll
    for (int ks = 0; ks < 4; ++ks) {
      oat0 = MFMA32(vf0[ks], pbf[ks], oat0);
      oat1 = MFMA32(vf1[ks], pbf[ks], oat1);
    }
    __builtin_amdgcn_s_setprio(0);

    if (t + 1 < NT) RAWBAR();   // all waves done reading buf[pb] before overwrite
  }

  // combine l across the two kpos halves (lane <-> lane+32), then epilogue
  u32x2 sr = __builtin_amdgcn_permlane32_swap(__float_as_uint(l_i),
                                              __float_as_uint(l_i), false, false);
  float l = __uint_as_float(sr[0]) + __uint_as_float(sr[1]);
  float qm = qmask[(size_t)bh * TT + q0 + l31];
  float sc = qm / fmaxf(l, 1e-30f);
  unsigned short* ob = O + ((size_t)(b * TT + q0 + l31)) * DD + h * DH + h2 * 4;
#pragma unroll
  for (int qq = 0; qq < 4; ++qq) {
    us4 w0, w1;
#pragma unroll
    for (int i = 0; i < 4; ++i) {
      w0[i] = f2bf(oat0[4 * qq + i] * sc);
      w1[i] = f2bf(oat1[4 * qq + i] * sc);
    }
    *(us4*)(ob + 8 * qq) = w0;
    *(us4*)(ob + 32 + 8 * qq) = w1;
  }
}

// ---------------- 5. residual + LayerNorm (O in bf16) ----------------
__global__ __launch_bounds__(256) void ln_kernel(const unsigned short* __restrict__ O,
                                                 const float* __restrict__ qin,
                                                 const float* __restrict__ gamma,
                                                 const float* __restrict__ beta,
                                                 float* __restrict__ out) {
  int row = blockIdx.x * 4 + (threadIdx.x >> 6);
  int lane = threadIdx.x & 63;
  size_t base = (size_t)row * DD + lane * 8;
  us8 o = *(const us8*)(O + base);
  const float4* q4 = (const float4*)(qin + base);
  float4 c = q4[0], d2 = q4[1];
  float qv[8] = {c.x, c.y, c.z, c.w, d2.x, d2.y, d2.z, d2.w};
  float v[8];
#pragma unroll
  for (int j = 0; j < 8; ++j) v[j] = bf2f(o[j]) + qv[j];
  float s = 0.f, s2 = 0.f;
#pragma unroll
  for (int j = 0; j < 8; ++j) { s += v[j]; s2 += v[j] * v[j]; }
#pragma unroll
  for (int xm = 1; xm < 64; xm <<= 1) {
    s += __shfl_xor(s, xm);
    s2 += __shfl_xor(s2, xm);
  }
  float mu = s * (1.0f / DD);
  float var = s2 * (1.0f / DD) - mu * mu;
  float rs = rsqrtf(var + 1e-3f);
  const float* g = gamma + lane * 8;
  const float* bb = beta + lane * 8;
  float* ob = out + base;
#pragma unroll
  for (int j = 0; j < 8; ++j) ob[j] = (v[j] - mu) * rs * g[j] + bb[j];
}

// ---------------- launch ----------------
extern "C" void kernel_launch(void* const* d_in, const int* in_sizes, int n_in,
                              void* d_out, int out_size, void* d_ws, size_t ws_size,
                              hipStream_t stream) {
  (void)in_sizes; (void)n_in; (void)out_size; (void)ws_size;
  const float* queries = (const float*)d_in[0];
  const float* keys_in = (const float*)d_in[1];
  const float* Wq = (const float*)d_in[2];
  const float* bq = (const float*)d_in[3];
  const float* Wk = (const float*)d_in[4];
  const float* bk = (const float*)d_in[5];
  const float* Wv = (const float*)d_in[6];
  const float* bv = (const float*)d_in[7];
  const float* gamma = (const float*)d_in[8];
  const float* beta  = (const float*)d_in[9];
  float* out = (float*)d_out;

  char* ws = (char*)d_ws;
  unsigned short* qb = (unsigned short*)(ws);            // [0,8 MB)  dead after gemm
  unsigned short* kb = (unsigned short*)(ws + (8ull << 20));  // dead after gemm
  unsigned short* Obf = (unsigned short*)(ws);           // bf16 O, aliases qb
  unsigned short* Qp = (unsigned short*)(ws + (16ull << 20));
  unsigned short* Kp = (unsigned short*)(ws + (24ull << 20));
  unsigned short* Vp = (unsigned short*)(ws + (32ull << 20));
  unsigned short* Vt = (unsigned short*)(ws + (40ull << 20));
  unsigned short* Wt = (unsigned short*)(ws + (48ull << 20));
  float* qmaskp = (float*)(ws + (50ull << 20));
  uint2* kbitsp = (uint2*)(ws + (50ull << 20) + (512ull << 10));

  prep_kernel<<<4864, 256, 0, stream>>>((const float4*)queries, (const float4*)keys_in,
                                        (us4*)qb, (us4*)kb, Wq, Wk, Wv, Wt);
  gemm_proj<<<dim3(64, 4, 3), 256, 0, stream>>>(qb, kb, Wt, bq, bk, bv,
                                                Qp, Kp, Vp, qmaskp, kbitsp);
  post_v<<<1024, 256, 0, stream>>>(Vp, Vt);
  attn_kernel<<<512, 256, 0, stream>>>(Qp, Kp, Vt, kbitsp, qmaskp, Obf);
  ln_kernel<<<2048, 256, 0, stream>>>(Obf, queries, gamma, beta, out);
}